// Round 11
// baseline (81.391 us; speedup 1.0000x reference)
//
#include <hip/hip_runtime.h>
#include <hip/hip_bf16.h>

typedef short bf16x8 __attribute__((ext_vector_type(8)));
typedef float f32x16 __attribute__((ext_vector_type(16)));
typedef unsigned short u16;

#define B 128
#define LQ 32
#define LK 128
#define D 128
#define REPS 4   // DIAGNOSTIC: amplify maxsim body for timing/rocprof separation

// ws layout:
//   lbf : fragment-ordered l, [x][ks(8)][hh(2)][rr(32)] x 16B  (1 MiB @ 0)
//   rbf : fragment-ordered r, [y][mj(4)][ks(8)][hh(2)][rr(32)] x 16B (4 MiB @ 1M)
//   sims: B*B f32 (64 KiB @ 5M)
// 32x32x16 MFMA fragment: lane = hh*32 + rr holds 8 elems, k = ks*16+hh*8+e;
// rr = A-row / B-col. Verified rounds 3-5/8/9/10 (absmax 0).

static __device__ inline u16 f2bf_rne(float f) {
  union { float f; unsigned u; } v; v.f = f;
  unsigned r = v.u + 0x7fffu + ((v.u >> 16) & 1u);
  return (u16)(r >> 16);
}

// One wave per row. Normalize, cast to bf16, store in MFMA-fragment order.
__global__ __launch_bounds__(256) void normalize_kernel(
    const float* __restrict__ left, const float* __restrict__ right,
    char* __restrict__ lbf, char* __restrict__ rbf) {
  int wave = (blockIdx.x * blockDim.x + threadIdx.x) >> 6;
  int lane = threadIdx.x & 63;
  const int n_l = B * LQ;
  const float* src; char* dst;
  if (wave < n_l) {
    src = left + (size_t)wave * D;
    dst = lbf + (wave >> 5) * 8192 + (wave & 31) * 16;
  } else {
    int row = wave - n_l;
    src = right + (size_t)row * D;
    dst = rbf + (row >> 7) * 32768 + ((row >> 5) & 3) * 8192 + (row & 31) * 16;
  }
  float2 v = *reinterpret_cast<const float2*>(src + lane * 2);
  float ss = v.x * v.x + v.y * v.y;
#pragma unroll
  for (int off = 1; off < 64; off <<= 1) ss += __shfl_xor(ss, off);
  float inv = 1.0f / fmaxf(sqrtf(ss), 1e-12f);
  unsigned packed = (unsigned)f2bf_rne(v.x * inv) |
                    ((unsigned)f2bf_rne(v.y * inv) << 16);
  *reinterpret_cast<unsigned*>(
      dst + (lane >> 3) * 1024 + ((lane >> 2) & 1) * 512 + (lane & 3) * 4) = packed;
}

// R10 maxsim body, repeated REPS times (internal, non-unrolled) purely to make
// its cost visible: dur(maxsim) ~ REPS * tau, and total = base + REPS*tau.
// Opaque asm on the rbf base per rep prevents cross-rep CSE (rule #17).
__global__ __launch_bounds__(256, 2) void maxsim_kernel(
    const char* __restrict__ lbf, const char* __restrict__ rbf,
    float* __restrict__ sims) {
  const int lane = threadIdx.x & 63;
  const int wv   = threadIdx.x >> 6;   // 0..3
  const int xg   = blockIdx.x >> 5;    // 0..15
  const int yg   = blockIdx.x & 31;    // 0..31
  const int x0   = xg * 8 + wv * 2;
  const int lane16 = lane * 16;

  bf16x8 bfr[2][8];
#pragma unroll
  for (int xi = 0; xi < 2; ++xi)
#pragma unroll
    for (int ks = 0; ks < 8; ++ks)
      bfr[xi][ks] = *reinterpret_cast<const bf16x8*>(
          lbf + (x0 + xi) * 8192 + ks * 1024 + lane16);

  f32x16 z;
#pragma unroll
  for (int t = 0; t < 16; ++t) z[t] = 0.f;

#define LOADA(dst, s_next)                                                   \
  {                                                                          \
    const char* nb = rb0 + (s_next) * 8192;                                  \
    _Pragma("unroll")                                                        \
    for (int ks = 0; ks < 8; ++ks)                                           \
      dst[ks] = *reinterpret_cast<const bf16x8*>(nb + ks * 1024 + lane16);   \
  }

#define MFMAB(srcA)                                                          \
  __builtin_amdgcn_s_setprio(1);                                             \
  a0 = __builtin_amdgcn_mfma_f32_32x32x16_bf16(srcA[0], bfr[0][0], z, 0, 0, 0); \
  a1 = __builtin_amdgcn_mfma_f32_32x32x16_bf16(srcA[0], bfr[1][0], z, 0, 0, 0); \
  _Pragma("unroll")                                                          \
  for (int ks = 1; ks < 8; ++ks) {                                           \
    a0 = __builtin_amdgcn_mfma_f32_32x32x16_bf16(srcA[ks], bfr[0][ks], a0, 0, 0, 0); \
    a1 = __builtin_amdgcn_mfma_f32_32x32x16_bf16(srcA[ks], bfr[1][ks], a1, 0, 0, 0); \
  }                                                                          \
  __builtin_amdgcn_s_setprio(0);

#define FOLD()                                                               \
  _Pragma("unroll")                                                          \
  for (int t = 0; t < 16; t += 4) {                                          \
    cm0 = fmaxf(cm0, fmaxf(fmaxf(a0[t], a0[t + 1]), fmaxf(a0[t + 2], a0[t + 3]))); \
    cm1 = fmaxf(cm1, fmaxf(fmaxf(a1[t], a1[t + 1]), fmaxf(a1[t + 2], a1[t + 3]))); \
  }

#define STEP(s, CUR, PF)                                                     \
  if ((s) + 2 < 16) LOADA(PF, (s) + 2);                                      \
  MFMAB(CUR);                                                                \
  FOLD();

#define EPI(yy)                                                              \
  cm0 = fmaxf(cm0, __shfl_xor(cm0, 32));                                     \
  cm1 = fmaxf(cm1, __shfl_xor(cm1, 32));                                     \
  _Pragma("unroll")                                                          \
  for (int off = 1; off <= 16; off <<= 1) {                                  \
    cm0 += __shfl_xor(cm0, off);                                             \
    cm1 += __shfl_xor(cm1, off);                                             \
  }                                                                          \
  if (lane == 0) {                                                           \
    sims[(x0 + 0) * B + (yg * 4 + (yy))] = cm0;                              \
    sims[(x0 + 1) * B + (yg * 4 + (yy))] = cm1;                              \
  }

  unsigned long long rbu =
      (unsigned long long)(rbf + (size_t)(yg * 4) * 32768);

#pragma unroll 1
  for (int rep = 0; rep < REPS; ++rep) {
    asm volatile("" : "+s"(rbu));        // opaque: block cross-rep CSE/hoist
    const char* rb0 = (const char*)rbu;

    bf16x8 p0[8], p1[8], p2[8];
    f32x16 a0, a1;
    float cm0, cm1;

    LOADA(p0, 0);
    LOADA(p1, 1);

    cm0 = cm1 = -3.0e38f;
    STEP(0,  p0, p2); STEP(1,  p1, p0); STEP(2,  p2, p1); STEP(3,  p0, p2);
    EPI(0);
    cm0 = cm1 = -3.0e38f;
    STEP(4,  p1, p0); STEP(5,  p2, p1); STEP(6,  p0, p2); STEP(7,  p1, p0);
    EPI(1);
    cm0 = cm1 = -3.0e38f;
    STEP(8,  p2, p1); STEP(9,  p0, p2); STEP(10, p1, p0); STEP(11, p2, p1);
    EPI(2);
    cm0 = cm1 = -3.0e38f;
    STEP(12, p0, p2); STEP(13, p1, p0); STEP(14, p2, p1); STEP(15, p0, p1);
    EPI(3);
  }

#undef LOADA
#undef MFMAB
#undef FOLD
#undef STEP
#undef EPI
}

// log-softmax + CE. 1 block, 1024 threads = 16 waves; wave w -> rows w*8..+7.
__global__ __launch_bounds__(1024) void loss_kernel(
    const float* __restrict__ sims, const float* __restrict__ logit_scale,
    const int* __restrict__ pos_idx, float* __restrict__ out) {
  __shared__ float red[16];
  const int lane = threadIdx.x & 63;
  const int wv   = threadIdx.x >> 6;
  const float scale = expf(logit_scale[0]);
  float local = 0.f;
#pragma unroll
  for (int rr = 0; rr < 8; ++rr) {
    const int x = wv * 8 + rr;
    const float* row = sims + x * B;
    float a = row[lane], b2 = row[64 + lane];
    float m = fmaxf(a, b2);
#pragma unroll
    for (int off = 1; off < 64; off <<= 1) m = fmaxf(m, __shfl_xor(m, off));
    float ml = scale * m;
    float e = expf(scale * a - ml) + expf(scale * b2 - ml);
#pragma unroll
    for (int off = 1; off < 64; off <<= 1) e += __shfl_xor(e, off);
    int pos = pos_idx[x];
    float pv = __shfl(pos < 64 ? a : b2, pos & 63);
    local += -(scale * pv - ml - logf(e));
  }
  if (lane == 0) red[wv] = local;
  __syncthreads();
  if (threadIdx.x == 0) {
    float t = 0.f;
#pragma unroll
    for (int i = 0; i < 16; ++i) t += red[i];
    out[0] = t / (float)B;
  }
}

extern "C" void kernel_launch(void* const* d_in, const int* in_sizes, int n_in,
                              void* d_out, int out_size, void* d_ws, size_t ws_size,
                              hipStream_t stream) {
  const float* left  = (const float*)d_in[0];
  const float* right = (const float*)d_in[1];
  const float* ls    = (const float*)d_in[2];
  const int*   pos   = (const int*)d_in[3];
  float* out = (float*)d_out;

  char* ws  = (char*)d_ws;
  char* lbf = ws;                                   // 1 MiB
  char* rbf = ws + (size_t)(1 << 20);               // 4 MiB
  float* sims = (float*)(ws + (size_t)(5 << 20));   // 64 KiB

  int waves = B * LQ + B * LK;  // 20480 rows
  normalize_kernel<<<waves / 4, 256, 0, stream>>>(left, right, lbf, rbf);
  maxsim_kernel<<<512, 256, 0, stream>>>(lbf, rbf, sims);
  loss_kernel<<<1, 1024, 0, stream>>>(sims, ls, pos, out);
}

// Round 12
// 35.460 us; speedup vs baseline: 2.2953x; 2.2953x over previous
//
#include <hip/hip_runtime.h>
#include <hip/hip_bf16.h>

typedef short bf16x8 __attribute__((ext_vector_type(8)));
typedef float f32x16 __attribute__((ext_vector_type(16)));
typedef unsigned short u16;

#define B 128
#define LQ 32
#define LK 128
#define D 128

// ws layout:
//   lbf : fragment-ordered l, [x][ks(8)][hh(2)][rr(32)] x 16B  (1 MiB @ 0)
//   rbf : fragment-ordered r, [y][mj(4)][ks(8)][hh(2)][rr(32)] x 16B (4 MiB @ 1M)
//   sims: B*B f32 (64 KiB @ 5M)
// 32x32x16 MFMA fragment: lane = hh*32 + rr holds 8 elems, k = ks*16+hh*8+e;
// rr = A-row / B-col. Verified rounds 3-5/8/9/10/11 (absmax 0).
//
// XCD co-location (R11 finding: cold first-touch = 2x tile cost): maxsim
// block bid consumes rbf region yg = bid&63; its XCD = bid%8 = yg%8.
// normalize uses the SAME grid shape so region yg is written only by blocks
// with bid%8 = yg%8 -> first touch is same-XCD L2.

static __device__ inline u16 f2bf_rne(float f) {
  union { float f; unsigned u; } v; v.f = f;
  unsigned r = v.u + 0x7fffu + ((v.u >> 16) & 1u);
  return (u16)(r >> 16);
}

// 1024 blocks x 4 waves. Block b (yg=b&63, xg=b>>6): wave wv normalizes
// 4 rows of rbf region yg (rows yg*256 + xg*16 + wv*4 + t) and 1 lbf row
// (b*4 + wv). All rows: 1024*(16+4) = 20480.
__global__ __launch_bounds__(256) void normalize_kernel(
    const float* __restrict__ left, const float* __restrict__ right,
    char* __restrict__ lbf, char* __restrict__ rbf) {
  const int lane = threadIdx.x & 63;
  const int wv   = threadIdx.x >> 6;
  const int b    = blockIdx.x;
  const int yg   = b & 63, xg = b >> 6;

  int   rrow[5];
  const float* srcs[5];
#pragma unroll
  for (int t = 0; t < 4; ++t) {
    rrow[t] = yg * 256 + xg * 16 + wv * 4 + t;       // rbf row
    srcs[t] = right + (size_t)rrow[t] * D;
  }
  rrow[4] = b * 4 + wv;                              // lbf row
  srcs[4] = left + (size_t)rrow[4] * D;

  float2 v[5];
#pragma unroll
  for (int t = 0; t < 5; ++t)
    v[t] = *reinterpret_cast<const float2*>(srcs[t] + lane * 2);

  const unsigned lslot =
      (lane >> 3) * 1024u + ((lane >> 2) & 1) * 512u + (lane & 3) * 4u;
#pragma unroll
  for (int t = 0; t < 5; ++t) {
    float ss = v[t].x * v[t].x + v[t].y * v[t].y;
#pragma unroll
    for (int off = 1; off < 64; off <<= 1) ss += __shfl_xor(ss, off);
    float inv = 1.0f / fmaxf(sqrtf(ss), 1e-12f);
    unsigned packed = (unsigned)f2bf_rne(v[t].x * inv) |
                      ((unsigned)f2bf_rne(v[t].y * inv) << 16);
    char* dst;
    if (t < 4) {
      int r2 = rrow[t];
      dst = rbf + (r2 >> 7) * 32768 + ((r2 >> 5) & 3) * 8192 + (r2 & 31) * 16;
    } else {
      int lr = rrow[4];
      dst = lbf + (lr >> 5) * 8192 + (lr & 31) * 16;
    }
    *reinterpret_cast<unsigned*>(dst + lslot) = packed;
  }
}

// Per (x,y): T[j][i] = sum_k r[y][j][k]*l[x][i][k] via 32x32x16 bf16 MFMA;
// sim[x][y] = sum_i max_j T. Fragment-ordered inputs -> contiguous 1KB wave
// loads; depth-3 rotating prefetch. Grid 16 xg * 64 yg = 1024 blocks,
// 2 y/block -> 4 blocks/CU (16 waves/CU) at VGPR~120.
__global__ __launch_bounds__(256, 2) void maxsim_kernel(
    const char* __restrict__ lbf, const char* __restrict__ rbf,
    float* __restrict__ sims) {
  const int lane = threadIdx.x & 63;
  const int wv   = threadIdx.x >> 6;   // 0..3
  const int xg   = blockIdx.x >> 6;    // 0..15
  const int yg   = blockIdx.x & 63;    // 0..63
  const int x0   = xg * 8 + wv * 2;
  const int lane16 = lane * 16;

  bf16x8 bfr[2][8];
#pragma unroll
  for (int xi = 0; xi < 2; ++xi)
#pragma unroll
    for (int ks = 0; ks < 8; ++ks)
      bfr[xi][ks] = *reinterpret_cast<const bf16x8*>(
          lbf + (x0 + xi) * 8192 + ks * 1024 + lane16);

  f32x16 z;
#pragma unroll
  for (int t = 0; t < 16; ++t) z[t] = 0.f;

  // 2 y-tiles (64 KB) contiguous; tile s (s = yy*4+mj) at s*8192.
  const char* rb0 = rbf + (size_t)yg * 2 * 32768;

#define LOADA(dst, s_next)                                                   \
  {                                                                          \
    const char* nb = rb0 + (s_next) * 8192;                                  \
    _Pragma("unroll")                                                        \
    for (int ks = 0; ks < 8; ++ks)                                           \
      dst[ks] = *reinterpret_cast<const bf16x8*>(nb + ks * 1024 + lane16);   \
  }

#define MFMAB(srcA)                                                          \
  __builtin_amdgcn_s_setprio(1);                                             \
  a0 = __builtin_amdgcn_mfma_f32_32x32x16_bf16(srcA[0], bfr[0][0], z, 0, 0, 0); \
  a1 = __builtin_amdgcn_mfma_f32_32x32x16_bf16(srcA[0], bfr[1][0], z, 0, 0, 0); \
  _Pragma("unroll")                                                          \
  for (int ks = 1; ks < 8; ++ks) {                                           \
    a0 = __builtin_amdgcn_mfma_f32_32x32x16_bf16(srcA[ks], bfr[0][ks], a0, 0, 0, 0); \
    a1 = __builtin_amdgcn_mfma_f32_32x32x16_bf16(srcA[ks], bfr[1][ks], a1, 0, 0, 0); \
  }                                                                          \
  __builtin_amdgcn_s_setprio(0);

#define FOLD()                                                               \
  _Pragma("unroll")                                                          \
  for (int t = 0; t < 16; t += 4) {                                          \
    cm0 = fmaxf(cm0, fmaxf(fmaxf(a0[t], a0[t + 1]), fmaxf(a0[t + 2], a0[t + 3]))); \
    cm1 = fmaxf(cm1, fmaxf(fmaxf(a1[t], a1[t + 1]), fmaxf(a1[t + 2], a1[t + 3]))); \
  }

#define STEP(s, CUR, PF)                                                     \
  if ((s) + 2 < 8) LOADA(PF, (s) + 2);                                       \
  MFMAB(CUR);                                                                \
  FOLD();

#define EPI(yy)                                                              \
  cm0 = fmaxf(cm0, __shfl_xor(cm0, 32));                                     \
  cm1 = fmaxf(cm1, __shfl_xor(cm1, 32));                                     \
  _Pragma("unroll")                                                          \
  for (int off = 1; off <= 16; off <<= 1) {                                  \
    cm0 += __shfl_xor(cm0, off);                                             \
    cm1 += __shfl_xor(cm1, off);                                             \
  }                                                                          \
  if (lane == 0) {                                                           \
    sims[(x0 + 0) * B + (yg * 2 + (yy))] = cm0;                              \
    sims[(x0 + 1) * B + (yg * 2 + (yy))] = cm1;                              \
  }

  bf16x8 p0[8], p1[8], p2[8];
  f32x16 a0, a1;
  float cm0, cm1;

  LOADA(p0, 0);
  LOADA(p1, 1);

  cm0 = cm1 = -3.0e38f;
  STEP(0, p0, p2); STEP(1, p1, p0); STEP(2, p2, p1); STEP(3, p0, p2);
  EPI(0);
  cm0 = cm1 = -3.0e38f;
  STEP(4, p1, p0); STEP(5, p2, p1); STEP(6, p0, p2); STEP(7, p1, p0);
  EPI(1);

#undef LOADA
#undef MFMAB
#undef FOLD
#undef STEP
#undef EPI
}

// log-softmax + CE. 1 block, 1024 threads = 16 waves; wave w -> rows w*8..+7.
__global__ __launch_bounds__(1024) void loss_kernel(
    const float* __restrict__ sims, const float* __restrict__ logit_scale,
    const int* __restrict__ pos_idx, float* __restrict__ out) {
  __shared__ float red[16];
  const int lane = threadIdx.x & 63;
  const int wv   = threadIdx.x >> 6;
  const float scale = expf(logit_scale[0]);
  float local = 0.f;
#pragma unroll
  for (int rr = 0; rr < 8; ++rr) {
    const int x = wv * 8 + rr;
    const float* row = sims + x * B;
    float a = row[lane], b2 = row[64 + lane];
    float m = fmaxf(a, b2);
#pragma unroll
    for (int off = 1; off < 64; off <<= 1) m = fmaxf(m, __shfl_xor(m, off));
    float ml = scale * m;
    float e = expf(scale * a - ml) + expf(scale * b2 - ml);
#pragma unroll
    for (int off = 1; off < 64; off <<= 1) e += __shfl_xor(e, off);
    int pos = pos_idx[x];
    float pv = __shfl(pos < 64 ? a : b2, pos & 63);
    local += -(scale * pv - ml - logf(e));
  }
  if (lane == 0) red[wv] = local;
  __syncthreads();
  if (threadIdx.x == 0) {
    float t = 0.f;
#pragma unroll
    for (int i = 0; i < 16; ++i) t += red[i];
    out[0] = t / (float)B;
  }
}

extern "C" void kernel_launch(void* const* d_in, const int* in_sizes, int n_in,
                              void* d_out, int out_size, void* d_ws, size_t ws_size,
                              hipStream_t stream) {
  const float* left  = (const float*)d_in[0];
  const float* right = (const float*)d_in[1];
  const float* ls    = (const float*)d_in[2];
  const int*   pos   = (const int*)d_in[3];
  float* out = (float*)d_out;

  char* ws  = (char*)d_ws;
  char* lbf = ws;                                   // 1 MiB
  char* rbf = ws + (size_t)(1 << 20);               // 4 MiB
  float* sims = (float*)(ws + (size_t)(5 << 20));   // 64 KiB

  normalize_kernel<<<1024, 256, 0, stream>>>(left, right, lbf, rbf);
  maxsim_kernel<<<1024, 256, 0, stream>>>(lbf, rbf, sims);
  loss_kernel<<<1, 1024, 0, stream>>>(sims, ls, pos, out);
}